// Round 8
// baseline (244.875 us; speedup 1.0000x reference)
//
#include <hip/hip_runtime.h>
#include <math.h>

#define Gn 64
#define Nn 1000
#define En 8192
#define Cc 128
#define HIDn 256
#define EPSf 1e-5f

typedef __attribute__((ext_vector_type(8))) short bh8;
typedef __attribute__((ext_vector_type(4))) float fx4;

__device__ __forceinline__ unsigned short f2bf(float f) {
    unsigned u = __float_as_uint(f);
    u += 0x7fffu + ((u >> 16) & 1u);
    return (unsigned short)(u >> 16);
}
__device__ __forceinline__ float bflo(unsigned u) { return __uint_as_float(u << 16); }
__device__ __forceinline__ float bfhi(unsigned u) { return __uint_as_float(u & 0xffff0000u); }

// ---------------- pre: blocks 0..255 convert X->bf16 (4/graph) | 256..319 prep(graph b-256) -
__global__ __launch_bounds__(256) void k_pre(const int* __restrict__ ei, const float* __restrict__ X,
                                             int4* __restrict__ ninfo, int2* __restrict__ epair,
                                             float* __restrict__ pooled, float* __restrict__ repr,
                                             int* __restrict__ ctr, unsigned short* __restrict__ Xb)
{
    __shared__ int   curs[1024];
    __shared__ float dinv_s[1024];
    __shared__ int   wsum[4];
    int t = threadIdx.x;

    if (blockIdx.x < 256) {
        // ---------------- convert: X (fp32) -> Xb (bf16), XCD-affine ----------------
        int cb = blockIdx.x;
        int xcd = cb & 7, gg = (cb >> 3) & 7, q = cb >> 6;   // graph on XCD g%8
        int g = xcd + 8 * gg;
        const float* Xg = X + (size_t)g * Nn * Cc + (size_t)q * 250 * Cc;
        unsigned short* Xo = Xb + (size_t)g * Nn * Cc + (size_t)q * 250 * Cc;
        for (int idx = t; idx < 4000; idx += 256) {          // 250 rows * 16 chunks of 8
            const float* p = Xg + (size_t)idx * 8;
            fx4 a0 = *(const fx4*)p;
            fx4 a1 = *(const fx4*)(p + 4);
            bh8 v;
            v[0] = (short)f2bf(a0[0]); v[1] = (short)f2bf(a0[1]);
            v[2] = (short)f2bf(a0[2]); v[3] = (short)f2bf(a0[3]);
            v[4] = (short)f2bf(a1[0]); v[5] = (short)f2bf(a1[1]);
            v[6] = (short)f2bf(a1[2]); v[7] = (short)f2bf(a1[3]);
            *(bh8*)(Xo + (size_t)idx * 8) = v;
        }
        return;
    }

    // ---------------- prep (256 threads, wave-scan) ----------------
    int g = blockIdx.x - 256;                  // XCD g%8 (256 % 8 == 0)
    const int* srcp = ei + (size_t)g * 2 * En;
    const int* dstp = srcp + En;
    int lane = t & 63, wv = t >> 6;

    #pragma unroll
    for (int j = 0; j < 4; ++j) curs[t * 4 + j] = 0;
    __syncthreads();
    for (int e = t; e < En; e += 256) atomicAdd(&curs[dstp[e]], 1);
    __syncthreads();

    int base = t * 4;
    int d0 = curs[base], d1 = curs[base + 1], d2 = curs[base + 2], d3 = curs[base + 3];
    int s = d0 + d1 + d2 + d3;
    int v = s;
    #pragma unroll
    for (int off = 1; off <= 32; off <<= 1) {
        int u = __shfl_up(v, off);
        if (lane >= off) v += u;
    }
    if (lane == 63) wsum[wv] = v;
    __syncthreads();
    int woff = 0;
    #pragma unroll
    for (int w = 0; w < 4; ++w) if (w < wv) woff += wsum[w];
    int e0 = woff + v - s;
    int e1 = e0 + d0, e2 = e1 + d1, e3 = e2 + d2;
    float dv0 = rsqrtf((float)d0 + 1.f), dv1 = rsqrtf((float)d1 + 1.f);
    float dv2 = rsqrtf((float)d2 + 1.f), dv3 = rsqrtf((float)d3 + 1.f);
    curs[base] = e0; curs[base + 1] = e1; curs[base + 2] = e2; curs[base + 3] = e3;
    dinv_s[base] = dv0; dinv_s[base + 1] = dv1; dinv_s[base + 2] = dv2; dinv_s[base + 3] = dv3;
    if (base < Nn)     ninfo[g * Nn + base]     = make_int4(e0, d0, __float_as_int(dv0 * dv0), 0);
    if (base + 1 < Nn) ninfo[g * Nn + base + 1] = make_int4(e1, d1, __float_as_int(dv1 * dv1), 0);
    if (base + 2 < Nn) ninfo[g * Nn + base + 2] = make_int4(e2, d2, __float_as_int(dv2 * dv2), 0);
    if (base + 3 < Nn) ninfo[g * Nn + base + 3] = make_int4(e3, d3, __float_as_int(dv3 * dv3), 0);
    __syncthreads();

    for (int e = t; e < En; e += 256) {
        int dd = dstp[e], ss = srcp[e];
        int p = atomicAdd(&curs[dd], 1);
        float w = dinv_s[ss] * dinv_s[dd];
        epair[(size_t)g * En + p] = make_int2(ss, __float_as_int(w));
    }
    if (t < Cc) pooled[g * Cc + t] = 0.f;      // accumulated by k_layer<1>
    if (g == 0 && t < Cc) repr[t] = 0.f;       // accumulated by k_tailfinal
    if (g == 0 && t == 0) *ctr = 0;            // completion counter for k_tailfinal
}

// ---------------- layer: per block, gather Ahat*Xin rows -> LDS -> MFMA W -> tanh ----------
// POOL=0: write H (bf16). POOL=1: shuffle-reduce + atomic pool (no H write).
// 1024 blocks = 16 rblk/graph * 64 graphs, XCD-affine; 4 waves * 16 rows each.
template<int POOL>
__global__ __launch_bounds__(256) void k_layer(const unsigned* __restrict__ Xrows,
                                               const float* __restrict__ W,
                                               const float* __restrict__ bias,
                                               const int2* __restrict__ epair,
                                               const int4* __restrict__ ninfo,
                                               unsigned short* __restrict__ Hout,
                                               float* __restrict__ pooled)
{
    __shared__ __align__(16) short Wt[128][136];    // W^T fragments
    __shared__ __align__(16) short At[4][16][136];  // per-wave aggregated A tile (bf16)
    int b = blockIdx.x;
    int xcd = b & 7, gg = (b >> 3) & 7, rblk = b >> 6;  // graph on XCD g%8
    int g = xcd + 8 * gg;
    int t = threadIdx.x;
    for (int idx = t; idx < 16384; idx += 256) {
        int kI = idx >> 7, n = idx & 127;
        Wt[n][kI] = (short)f2bf(W[idx]);
    }
    __syncthreads();

    int wv = t >> 6, lane = t & 63;
    const unsigned* Xg = Xrows + (size_t)g * Nn * 64;   // rows of 64 u32 = 128 bf16
    const int2* epg = epair + (size_t)g * En;
    const int4* nig = ninfo + (size_t)g * Nn;
    int rbase = rblk * 64 + wv * 16;

    // ---- gather phase: 16 rows, wave-cooperative (lane = col pair), 4-deep unroll ----
    for (int rr = 0; rr < 16; ++rr) {
        int n = rbase + rr;
        unsigned packed = 0;
        if (n < Nn) {
            int4 ni = nig[n];
            int st = ni.x, dc = ni.y;
            float sw = __int_as_float(ni.z);
            unsigned hv = Xg[(size_t)n * 64 + lane];
            float a0x = bflo(hv) * sw, a0y = bfhi(hv) * sw;
            float a1x = 0.f, a1y = 0.f, a2x = 0.f, a2y = 0.f, a3x = 0.f, a3y = 0.f;
            int e = 0;
            for (; e + 4 <= dc; e += 4) {
                int2 p0 = epg[st + e];
                int2 p1 = epg[st + e + 1];
                int2 p2 = epg[st + e + 2];
                int2 p3 = epg[st + e + 3];
                unsigned r0 = Xg[(size_t)p0.x * 64 + lane];
                unsigned r1 = Xg[(size_t)p1.x * 64 + lane];
                unsigned r2 = Xg[(size_t)p2.x * 64 + lane];
                unsigned r3 = Xg[(size_t)p3.x * 64 + lane];
                float w0 = __int_as_float(p0.y), w1 = __int_as_float(p1.y);
                float w2 = __int_as_float(p2.y), w3 = __int_as_float(p3.y);
                a0x = fmaf(bflo(r0), w0, a0x); a0y = fmaf(bfhi(r0), w0, a0y);
                a1x = fmaf(bflo(r1), w1, a1x); a1y = fmaf(bfhi(r1), w1, a1y);
                a2x = fmaf(bflo(r2), w2, a2x); a2y = fmaf(bfhi(r2), w2, a2y);
                a3x = fmaf(bflo(r3), w3, a3x); a3y = fmaf(bfhi(r3), w3, a3y);
            }
            for (; e < dc; ++e) {
                int2 p0 = epg[st + e];
                unsigned r0 = Xg[(size_t)p0.x * 64 + lane];
                float w0 = __int_as_float(p0.y);
                a0x = fmaf(bflo(r0), w0, a0x); a0y = fmaf(bfhi(r0), w0, a0y);
            }
            float ax = (a0x + a1x) + (a2x + a3x);
            float ay = (a0y + a1y) + (a2y + a3y);
            packed = ((unsigned)f2bf(ay) << 16) | (unsigned)f2bf(ax);
        }
        *(unsigned*)&At[wv][rr][lane * 2] = packed;   // wave-private: no barrier needed
    }

    // ---- MFMA phase ----
    int lr = lane & 15, lg = lane >> 4;
    bh8 af[4];
    #pragma unroll
    for (int ks = 0; ks < 4; ++ks) af[ks] = *(const bh8*)&At[wv][lr][ks * 32 + lg * 8];
    fx4 acc[8];
    #pragma unroll
    for (int ct = 0; ct < 8; ++ct) acc[ct] = fx4{0.f, 0.f, 0.f, 0.f};
    #pragma unroll
    for (int ks = 0; ks < 4; ++ks) {
        #pragma unroll
        for (int ct = 0; ct < 8; ++ct) {
            bh8 bfr = *(const bh8*)(&Wt[ct * 16 + lr][ks * 32 + lg * 8]);
            acc[ct] = __builtin_amdgcn_mfma_f32_16x16x32_bf16(af[ks], bfr, acc[ct], 0, 0, 0);
        }
    }
    float bias_r[8];
    #pragma unroll
    for (int ct = 0; ct < 8; ++ct) bias_r[ct] = bias[ct * 16 + lr];

    // C/D layout: col = ct*16 + (lane&15), row = rbase + (lane>>4)*4 + reg
    if (POOL) {
        float psum[8];
        #pragma unroll
        for (int ct = 0; ct < 8; ++ct) psum[ct] = 0.f;
        #pragma unroll
        for (int ct = 0; ct < 8; ++ct) {
            #pragma unroll
            for (int rg = 0; rg < 4; ++rg) {
                int row = rbase + lg * 4 + rg;
                if (row < Nn) psum[ct] += tanhf(acc[ct][rg] + bias_r[ct]);
            }
        }
        #pragma unroll
        for (int ct = 0; ct < 8; ++ct) {
            psum[ct] += __shfl_xor(psum[ct], 16);
            psum[ct] += __shfl_xor(psum[ct], 32);
        }
        if (lane < 16) {
            #pragma unroll
            for (int ct = 0; ct < 8; ++ct)
                atomicAdd(&pooled[g * Cc + ct * 16 + lane], psum[ct]);
        }
    } else {
        unsigned short* Hg = Hout + (size_t)g * Nn * Cc;
        #pragma unroll
        for (int ct = 0; ct < 8; ++ct) {
            #pragma unroll
            for (int rg = 0; rg < 4; ++rg) {
                int row = rbase + lg * 4 + rg;
                if (row < Nn)
                    Hg[(size_t)row * Cc + ct * 16 + lr] = f2bf(tanhf(acc[ct][rg] + bias_r[ct]));
            }
        }
    }
}

// ---------------- qkv: one wave per output column (coalesced rows + shuffle reduce) -------
__global__ __launch_bounds__(1024) void k_qkv(const float* __restrict__ pooled, const float* __restrict__ in_w,
                                              const float* __restrict__ in_b, float* __restrict__ qkvb)
{
    int t = threadIdx.x, lane = t & 63, wv = t >> 6;
    int c = blockIdx.x * 16 + wv;          // 24 blocks * 16 waves = 384 columns
    const float* wr = in_w + c * Cc;
    float w0 = wr[lane], w1 = wr[64 + lane];
    float bias = in_b[c];
    for (int i = 0; i < Gn; ++i) {
        float p = fmaf(pooled[i * Cc + lane], w0, pooled[i * Cc + 64 + lane] * w1);
        #pragma unroll
        for (int off2 = 32; off2 > 0; off2 >>= 1) p += __shfl_xor(p, off2);
        if (lane == 0) qkvb[i * 384 + c] = p + bias;
    }
}

// ---------------- attn: per-head block, pure LDS ----------------
__global__ __launch_bounds__(1024) void k_attn(const float* __restrict__ qkvb, float* __restrict__ ob)
{
    __shared__ float q[64][33], kk[64][33], v[64][33];
    __shared__ float S[64][64];
    int h = blockIdx.x, t = threadIdx.x;

    for (int idx = t; idx < 2048; idx += 1024) {
        int i = idx >> 5, cc = idx & 31;
        q[i][cc]  = qkvb[i * 384 + h * 32 + cc];
        kk[i][cc] = qkvb[i * 384 + 128 + h * 32 + cc];
        v[i][cc]  = qkvb[i * 384 + 256 + h * 32 + cc];
    }
    __syncthreads();

    for (int idx = t; idx < 4096; idx += 1024) {
        int i = idx >> 6, jj = idx & 63;
        float acc = 0.f;
        #pragma unroll
        for (int d2 = 0; d2 < 32; ++d2) acc = fmaf(q[i][d2], kk[jj][d2], acc);
        S[i][jj] = acc * 0.17677669529663687f;
    }
    __syncthreads();

    int lane = t & 63, w = t >> 6;
    for (int r = w; r < 64; r += 16) {
        float val = S[r][lane];
        float m = val;
        #pragma unroll
        for (int off = 32; off > 0; off >>= 1) m = fmaxf(m, __shfl_xor(m, off));
        float e2 = expf(val - m);
        float ssum = e2;
        #pragma unroll
        for (int off = 32; off > 0; off >>= 1) ssum += __shfl_xor(ssum, off);
        S[r][lane] = e2 / ssum;
    }
    __syncthreads();

    for (int idx = t; idx < 2048; idx += 1024) {
        int i = idx >> 5, d2 = idx & 31;
        float acc = 0.f;
        #pragma unroll 4
        for (int k2 = 0; k2 < 64; ++k2) acc = fmaf(S[i][k2], v[k2][d2], acc);
        ob[i * Cc + h * 32 + d2] = acc;
    }
}

// ---------------- tail+final: 4 graphs/block; last-done block computes logits -------------
__global__ __launch_bounds__(1024) void k_tailfinal(const float* __restrict__ ob, const float* __restrict__ out_w,
                                                    const float* __restrict__ out_b, const float* __restrict__ mw1,
                                                    const float* __restrict__ mb1, const float* __restrict__ mw2,
                                                    const float* __restrict__ mb2, const float* __restrict__ ln2g,
                                                    const float* __restrict__ ln2b, const float* __restrict__ lw,
                                                    const float* __restrict__ lb, float* __restrict__ repr,
                                                    int* __restrict__ ctr, float* __restrict__ out)
{
    __shared__ float sob[4][128];
    __shared__ float sxatt[4][128];
    __shared__ float sm1[4][256];
    __shared__ float spart[4][128];
    __shared__ float pr[128];
    __shared__ int slast;
    int g0 = blockIdx.x * 4;                 // 16 blocks x 4 graphs
    int t = threadIdx.x, lane = t & 63, wv = t >> 6;

    if (t < 512) sob[t >> 7][t & 127] = ob[(size_t)(g0 + (t >> 7)) * Cc + (t & 127)];
    if (t < 128) pr[t] = 0.f;
    __syncthreads();

    // out-proj: wave per column, weight row register-resident, reused across 4 graphs
    for (int c = wv; c < Cc; c += 16) {
        float w0 = out_w[c * Cc + lane];
        float w1 = out_w[c * Cc + 64 + lane];
        float bc = out_b[c];
        #pragma unroll
        for (int g = 0; g < 4; ++g) {
            float p = fmaf(sob[g][lane], w0, sob[g][64 + lane] * w1);
            #pragma unroll
            for (int off = 32; off > 0; off >>= 1) p += __shfl_xor(p, off);
            if (lane == 0) sxatt[g][c] = p + bc;
        }
    }
    __syncthreads();

    // mlp1: 1024 threads = 256 cols x 4 graphs; mw1 coalesced along j
    {
        int j = t & 255, gi = t >> 8;
        float acc = mb1[j];
        #pragma unroll 8
        for (int k = 0; k < Cc; ++k) acc = fmaf(sxatt[gi][k], mw1[k * HIDn + j], acc);
        sm1[gi][j] = fmaxf(acc, 0.f);
    }
    __syncthreads();

    // mlp2 split-K: 1024 threads = 128 cols x 4 graphs x 2 K-halves; mw2 coalesced along c
    {
        int c = t & 127, gi = (t >> 7) & 3, half = t >> 9;
        int k0 = half * 128;
        float acc = 0.f;
        #pragma unroll 8
        for (int k = 0; k < 128; ++k) acc = fmaf(sm1[gi][k0 + k], mw2[(k0 + k) * Cc + c], acc);
        if (half) spart[gi][c] = acc;
        __syncthreads();
        if (!half) sxatt[gi][c] = sxatt[gi][c] + acc + spart[gi][c] + mb2[c];   // y (residual)
    }
    __syncthreads();

    // LN + relu + per-block accumulate (waves 0..3 = graphs)
    if (t < 256) {
        int g = wv;
        float v0 = sxatt[g][lane], v1 = sxatt[g][64 + lane];
        float s = v0 + v1;
        #pragma unroll
        for (int off = 32; off > 0; off >>= 1) s += __shfl_xor(s, off);
        float mu = s * (1.f / 128.f);
        float d0 = v0 - mu, d1 = v1 - mu;
        float vv = d0 * d0 + d1 * d1;
        #pragma unroll
        for (int off = 32; off > 0; off >>= 1) vv += __shfl_xor(vv, off);
        float rstd = rsqrtf(vv * (1.f / 128.f) + EPSf);
        float z0 = fmaxf(d0 * rstd * ln2g[lane] + ln2b[lane], 0.f);
        float z1 = fmaxf(d1 * rstd * ln2g[64 + lane] + ln2b[64 + lane], 0.f);
        atomicAdd(&pr[lane], z0);
        atomicAdd(&pr[64 + lane], z1);
    }
    __syncthreads();
    if (t < 128) atomicAdd(&repr[t], pr[t]);

    // completion: last-arriving block reduces repr -> logits
    __threadfence();
    __syncthreads();
    if (t == 0) slast = atomicAdd(ctr, 1);
    __syncthreads();
    if (slast == 15) {
        __threadfence();
        __shared__ float r0s[128], r1s[128];
        if (t < 128) {
            float r = __hip_atomic_load(&repr[t], __ATOMIC_RELAXED, __HIP_MEMORY_SCOPE_AGENT);
            r0s[t] = r * lw[t * 2 + 0];
            r1s[t] = r * lw[t * 2 + 1];
        }
        __syncthreads();
        for (int s2 = 64; s2 > 0; s2 >>= 1) {
            if (t < s2) { r0s[t] += r0s[t + s2]; r1s[t] += r1s[t + s2]; }
            __syncthreads();
        }
        if (t == 0) { out[0] = r0s[0] + lb[0]; out[1] = r1s[0] + lb[1]; }
    }
}

extern "C" void kernel_launch(void* const* d_in, const int* in_sizes, int n_in,
                              void* d_out, int out_size, void* d_ws, size_t ws_size,
                              hipStream_t stream)
{
    const float* x     = (const float*)d_in[0];
    const int*   ei    = (const int*)d_in[1];
    const float* W0    = (const float*)d_in[2];
    const float* b0    = (const float*)d_in[3];
    const float* W1    = (const float*)d_in[4];
    const float* b1    = (const float*)d_in[5];
    const float* in_w  = (const float*)d_in[6];
    const float* in_b  = (const float*)d_in[7];
    const float* out_w = (const float*)d_in[8];
    const float* out_b = (const float*)d_in[9];
    const float* ln2g  = (const float*)d_in[10];
    const float* ln2b  = (const float*)d_in[11];
    const float* mw1   = (const float*)d_in[12];
    const float* mb1   = (const float*)d_in[13];
    const float* mw2   = (const float*)d_in[14];
    const float* mb2   = (const float*)d_in[15];
    const float* lw    = (const float*)d_in[16];
    const float* lb    = (const float*)d_in[17];
    float* out = (float*)d_out;
    (void)in_sizes; (void)n_in; (void)out_size; (void)ws_size;

    char* ws = (char*)d_ws;
    size_t off = 0;
    auto carve = [&](size_t bytes) { size_t o = off; off += (bytes + 255) & ~(size_t)255; return o; };
    size_t o_ni    = carve((size_t)Gn * Nn * 16);
    size_t o_ep    = carve((size_t)Gn * En * 8);
    size_t o_pool  = carve((size_t)Gn * Cc * 4);
    size_t o_qkv   = carve((size_t)Gn * 384 * 4);
    size_t o_ob    = carve((size_t)Gn * Cc * 4);
    size_t o_repr  = carve((size_t)Cc * 4);
    size_t o_ctr   = carve(256);
    size_t o_H     = carve((size_t)Gn * Nn * Cc * 2);
    size_t o_Xb    = carve((size_t)Gn * Nn * Cc * 2);

    int4*  ninfo  = (int4*)(ws + o_ni);
    int2*  epair  = (int2*)(ws + o_ep);
    float* pooled = (float*)(ws + o_pool);
    float* qkvb   = (float*)(ws + o_qkv);
    float* ob     = (float*)(ws + o_ob);
    float* repr   = (float*)(ws + o_repr);
    int*   ctr    = (int*)(ws + o_ctr);
    unsigned short* H  = (unsigned short*)(ws + o_H);
    unsigned short* Xb = (unsigned short*)(ws + o_Xb);

    k_pre<<<320, 256, 0, stream>>>(ei, x, ninfo, epair, pooled, repr, ctr, Xb);
    k_layer<0><<<1024, 256, 0, stream>>>((const unsigned*)Xb, W0, b0, epair, ninfo, H, nullptr);
    k_layer<1><<<1024, 256, 0, stream>>>((const unsigned*)H, W1, b1, epair, ninfo, nullptr, pooled);
    k_qkv<<<24, 1024, 0, stream>>>(pooled, in_w, in_b, qkvb);
    k_attn<<<4, 1024, 0, stream>>>(qkvb, ob);
    k_tailfinal<<<16, 1024, 0, stream>>>(ob, out_w, out_b, mw1, mb1, mw2, mb2, ln2g, ln2b,
                                         lw, lb, repr, ctr, out);
}

// Round 9
// 215.781 us; speedup vs baseline: 1.1348x; 1.1348x over previous
//
#include <hip/hip_runtime.h>
#include <math.h>

#define Gn 64
#define Nn 1000
#define En 8192
#define Cc 128
#define HIDn 256
#define EPSf 1e-5f

typedef __attribute__((ext_vector_type(8))) short bh8;
typedef __attribute__((ext_vector_type(4))) float fx4;

__device__ __forceinline__ unsigned short f2bf(float f) {
    unsigned u = __float_as_uint(f);
    u += 0x7fffu + ((u >> 16) & 1u);
    return (unsigned short)(u >> 16);
}
__device__ __forceinline__ float bflo(unsigned u) { return __uint_as_float(u << 16); }
__device__ __forceinline__ float bfhi(unsigned u) { return __uint_as_float(u & 0xffff0000u); }

// ---- pre: blocks 0..2047 convert X->bf16 (32/graph, XCD-affine) | 2048..2111 prep ----
__global__ __launch_bounds__(256) void k_pre(const int* __restrict__ ei, const float* __restrict__ X,
                                             int4* __restrict__ ninfo, int2* __restrict__ epair,
                                             float* __restrict__ pooled, float* __restrict__ repr,
                                             int* __restrict__ ctr, unsigned short* __restrict__ Xb)
{
    __shared__ int   curs[1024];
    __shared__ float dinv_s[1024];
    __shared__ int   wsum[4];
    int t = threadIdx.x;

    if (blockIdx.x < 2048) {
        // streaming convert, high occupancy; graph g lands on XCD g%8
        int b = blockIdx.x;
        int xcd = b & 7, gg = (b >> 3) & 7, q = b >> 6;      // q: 0..31
        int g = xcd + 8 * gg;
        const float* Xg = X + (size_t)g * Nn * Cc + (size_t)q * 500 * 8;
        unsigned short* Xo = Xb + (size_t)g * Nn * Cc + (size_t)q * 500 * 8;
        for (int i = t; i < 500; i += 256) {
            const float* p = Xg + (size_t)i * 8;
            fx4 a0 = *(const fx4*)p;
            fx4 a1 = *(const fx4*)(p + 4);
            bh8 v;
            v[0] = (short)f2bf(a0[0]); v[1] = (short)f2bf(a0[1]);
            v[2] = (short)f2bf(a0[2]); v[3] = (short)f2bf(a0[3]);
            v[4] = (short)f2bf(a1[0]); v[5] = (short)f2bf(a1[1]);
            v[6] = (short)f2bf(a1[2]); v[7] = (short)f2bf(a1[3]);
            *(bh8*)(Xo + (size_t)i * 8) = v;
        }
        return;
    }

    // ---------------- prep (256 threads, wave-scan); 2048%8==0 so XCD g%8 ----------------
    int g = blockIdx.x - 2048;
    const int* srcp = ei + (size_t)g * 2 * En;
    const int* dstp = srcp + En;
    int lane = t & 63, wv = t >> 6;

    #pragma unroll
    for (int j = 0; j < 4; ++j) curs[t * 4 + j] = 0;
    __syncthreads();
    for (int e = t; e < En; e += 256) atomicAdd(&curs[dstp[e]], 1);
    __syncthreads();

    int base = t * 4;
    int d0 = curs[base], d1 = curs[base + 1], d2 = curs[base + 2], d3 = curs[base + 3];
    int s = d0 + d1 + d2 + d3;
    int v = s;
    #pragma unroll
    for (int off = 1; off <= 32; off <<= 1) {
        int u = __shfl_up(v, off);
        if (lane >= off) v += u;
    }
    if (lane == 63) wsum[wv] = v;
    __syncthreads();
    int woff = 0;
    #pragma unroll
    for (int w = 0; w < 4; ++w) if (w < wv) woff += wsum[w];
    int e0 = woff + v - s;
    int e1 = e0 + d0, e2 = e1 + d1, e3 = e2 + d2;
    float dv0 = rsqrtf((float)d0 + 1.f), dv1 = rsqrtf((float)d1 + 1.f);
    float dv2 = rsqrtf((float)d2 + 1.f), dv3 = rsqrtf((float)d3 + 1.f);
    curs[base] = e0; curs[base + 1] = e1; curs[base + 2] = e2; curs[base + 3] = e3;
    dinv_s[base] = dv0; dinv_s[base + 1] = dv1; dinv_s[base + 2] = dv2; dinv_s[base + 3] = dv3;
    if (base < Nn)     ninfo[g * Nn + base]     = make_int4(e0, d0, __float_as_int(dv0 * dv0), 0);
    if (base + 1 < Nn) ninfo[g * Nn + base + 1] = make_int4(e1, d1, __float_as_int(dv1 * dv1), 0);
    if (base + 2 < Nn) ninfo[g * Nn + base + 2] = make_int4(e2, d2, __float_as_int(dv2 * dv2), 0);
    if (base + 3 < Nn) ninfo[g * Nn + base + 3] = make_int4(e3, d3, __float_as_int(dv3 * dv3), 0);
    __syncthreads();

    for (int e = t; e < En; e += 256) {
        int dd = dstp[e], ss = srcp[e];
        int p = atomicAdd(&curs[dd], 1);
        float w = dinv_s[ss] * dinv_s[dd];
        epair[(size_t)g * En + p] = make_int2(ss, __float_as_int(w));
    }
    if (t < Cc) pooled[g * Cc + t] = 0.f;      // accumulated by k_combine<1>
    if (g == 0 && t < Cc) repr[t] = 0.f;       // accumulated by k_tailfinal
    if (g == 0 && t == 0) *ctr = 0;            // completion counter for k_tailfinal
}

// ---------------- gemm: H[g] = bf16(Xh[g] @ W), 4 blocks/graph, bf16 input ----------------
__global__ __launch_bounds__(256) void k_gemm(const unsigned short* __restrict__ Xh,
                                              const float* __restrict__ W,
                                              unsigned short* __restrict__ Hout)
{
    __shared__ __align__(16) short Wt[128][136];
    int b = blockIdx.x;
    int xcd = b & 7, j = b >> 3;
    int g = xcd + 8 * (j & 7);     // graph g on XCD g%8
    int rblk = j >> 3;             // 0..3, 256 rows each
    int t = threadIdx.x;
    for (int idx = t; idx < 16384; idx += 256) {
        int kI = idx >> 7, n = idx & 127;
        Wt[n][kI] = (short)f2bf(W[idx]);
    }
    __syncthreads();
    int wave = t >> 6, l = t & 63;
    int lr = l & 15, lg = l >> 4;
    const short* Xg = (const short*)Xh + (size_t)g * Nn * Cc;
    unsigned short* Hg = Hout + (size_t)g * Nn * Cc;

    for (int s = 0; s < 4; ++s) {
        int rbase = rblk * 256 + wave * 64 + s * 16;
        int r = rbase + lr;
        bool ok = r < Nn;
        bh8 af[4];
        #pragma unroll
        for (int ks = 0; ks < 4; ++ks) {
            if (ok) af[ks] = *(const bh8*)(Xg + (size_t)r * Cc + ks * 32 + lg * 8);
            else    af[ks] = bh8{0, 0, 0, 0, 0, 0, 0, 0};
        }
        fx4 acc[8];
        #pragma unroll
        for (int ct = 0; ct < 8; ++ct) acc[ct] = fx4{0.f, 0.f, 0.f, 0.f};
        #pragma unroll
        for (int ks = 0; ks < 4; ++ks) {
            #pragma unroll
            for (int ct = 0; ct < 8; ++ct) {
                bh8 bfr = *(const bh8*)(&Wt[ct * 16 + lr][ks * 32 + lg * 8]);
                acc[ct] = __builtin_amdgcn_mfma_f32_16x16x32_bf16(af[ks], bfr, acc[ct], 0, 0, 0);
            }
        }
        // C/D layout: col = lane&15, row = (lane>>4)*4 + reg
        #pragma unroll
        for (int ct = 0; ct < 8; ++ct) {
            #pragma unroll
            for (int rg = 0; rg < 4; ++rg) {
                int row = rbase + lg * 4 + rg;
                if (row < Nn) Hg[(size_t)row * Cc + ct * 16 + lr] = f2bf(acc[ct][rg]);
            }
        }
    }
}

// ------- combine: tanh(b + selfw*H[n] + sum_e w_e*H[src_e]); 8-deep branchless gather ------
template<int POOL>
__global__ __launch_bounds__(256) void k_combine(const unsigned* __restrict__ Hb, const int2* __restrict__ epair,
                                                 const int4* __restrict__ ninfo, const float* __restrict__ bias,
                                                 unsigned* __restrict__ Tout, float* __restrict__ pooled)
{
    int b = blockIdx.x;
    int xcd = b & 7, j = b >> 3;
    int g = xcd + 8 * (j & 7);     // same XCD as this graph's GEMM blocks
    int blk = j >> 3;              // 0..31
    int wave = threadIdx.x >> 6, lane = threadIdx.x & 63;
    const unsigned* Hg = Hb + (size_t)g * Nn * 64;   // rows of 64 uint = 128 bf16
    const int2* epg = epair + (size_t)g * En;
    const int4* nig = ninfo + (size_t)g * Nn;
    float2 bb = *(const float2*)(bias + lane * 2);
    float px = 0.f, py = 0.f;
    for (int n = blk * 4 + wave; n < Nn; n += 128) {
        int4 ni = nig[n];
        int st = ni.x, dc = ni.y;
        float sw = __int_as_float(ni.z);
        unsigned hv = Hg[n * 64 + lane];
        float ax0 = bflo(hv) * sw + bb.x, ay0 = bfhi(hv) * sw + bb.y;
        float axs[8], ays[8];
        axs[0] = ax0; ays[0] = ay0;
        #pragma unroll
        for (int jj = 1; jj < 8; ++jj) { axs[jj] = 0.f; ays[jj] = 0.f; }
        int rounds = (dc + 7) >> 3;            // wave-uniform
        for (int rd = 0; rd < rounds; ++rd) {
            int eb = st + rd * 8;
            int2 p[8];
            #pragma unroll
            for (int jj = 0; jj < 8; ++jj) {
                int idx = eb + jj;
                idx = idx < En ? idx : En - 1;      // clamped, always-valid load
                p[jj] = epg[idx];
            }
            unsigned r[8];
            #pragma unroll
            for (int jj = 0; jj < 8; ++jj) r[jj] = Hg[(size_t)p[jj].x * 64 + lane];
            #pragma unroll
            for (int jj = 0; jj < 8; ++jj) {
                float w = (rd * 8 + jj < dc) ? __int_as_float(p[jj].y) : 0.f;
                axs[jj] = fmaf(bflo(r[jj]), w, axs[jj]);
                ays[jj] = fmaf(bfhi(r[jj]), w, ays[jj]);
            }
        }
        float ax = ((axs[0] + axs[1]) + (axs[2] + axs[3])) + ((axs[4] + axs[5]) + (axs[6] + axs[7]));
        float ay = ((ays[0] + ays[1]) + (ays[2] + ays[3])) + ((ays[4] + ays[5]) + (ays[6] + ays[7]));
        float tx = tanhf(ax), ty = tanhf(ay);
        if (POOL) { px += tx; py += ty; }
        else Tout[(size_t)(g * Nn + n) * 64 + lane] = ((unsigned)f2bf(ty) << 16) | (unsigned)f2bf(tx);
    }
    if (POOL) {
        atomicAdd(&pooled[g * Cc + lane * 2], px);
        atomicAdd(&pooled[g * Cc + lane * 2 + 1], py);
    }
}

// ---------------- qkv: one wave per output column (coalesced rows + shuffle reduce) -------
__global__ __launch_bounds__(1024) void k_qkv(const float* __restrict__ pooled, const float* __restrict__ in_w,
                                              const float* __restrict__ in_b, float* __restrict__ qkvb)
{
    int t = threadIdx.x, lane = t & 63, wv = t >> 6;
    int c = blockIdx.x * 16 + wv;          // 24 blocks * 16 waves = 384 columns
    const float* wr = in_w + c * Cc;
    float w0 = wr[lane], w1 = wr[64 + lane];
    float bias = in_b[c];
    for (int i = 0; i < Gn; ++i) {
        float p = fmaf(pooled[i * Cc + lane], w0, pooled[i * Cc + 64 + lane] * w1);
        #pragma unroll
        for (int off2 = 32; off2 > 0; off2 >>= 1) p += __shfl_xor(p, off2);
        if (lane == 0) qkvb[i * 384 + c] = p + bias;
    }
}

// ---------------- attn: per-head block, pure LDS ----------------
__global__ __launch_bounds__(1024) void k_attn(const float* __restrict__ qkvb, float* __restrict__ ob)
{
    __shared__ float q[64][33], kk[64][33], v[64][33];
    __shared__ float S[64][64];
    int h = blockIdx.x, t = threadIdx.x;

    for (int idx = t; idx < 2048; idx += 1024) {
        int i = idx >> 5, cc = idx & 31;
        q[i][cc]  = qkvb[i * 384 + h * 32 + cc];
        kk[i][cc] = qkvb[i * 384 + 128 + h * 32 + cc];
        v[i][cc]  = qkvb[i * 384 + 256 + h * 32 + cc];
    }
    __syncthreads();

    for (int idx = t; idx < 4096; idx += 1024) {
        int i = idx >> 6, jj = idx & 63;
        float acc = 0.f;
        #pragma unroll
        for (int d2 = 0; d2 < 32; ++d2) acc = fmaf(q[i][d2], kk[jj][d2], acc);
        S[i][jj] = acc * 0.17677669529663687f;
    }
    __syncthreads();

    int lane = t & 63, w = t >> 6;
    for (int r = w; r < 64; r += 16) {
        float val = S[r][lane];
        float m = val;
        #pragma unroll
        for (int off = 32; off > 0; off >>= 1) m = fmaxf(m, __shfl_xor(m, off));
        float e2 = expf(val - m);
        float ssum = e2;
        #pragma unroll
        for (int off = 32; off > 0; off >>= 1) ssum += __shfl_xor(ssum, off);
        S[r][lane] = e2 / ssum;
    }
    __syncthreads();

    for (int idx = t; idx < 2048; idx += 1024) {
        int i = idx >> 5, d2 = idx & 31;
        float acc = 0.f;
        #pragma unroll 4
        for (int k2 = 0; k2 < 64; ++k2) acc = fmaf(S[i][k2], v[k2][d2], acc);
        ob[i * Cc + h * 32 + d2] = acc;
    }
}

// ---------------- tail+final: 4 graphs/block; last-done block computes logits -------------
__global__ __launch_bounds__(1024) void k_tailfinal(const float* __restrict__ ob, const float* __restrict__ out_w,
                                                    const float* __restrict__ out_b, const float* __restrict__ mw1,
                                                    const float* __restrict__ mb1, const float* __restrict__ mw2,
                                                    const float* __restrict__ mb2, const float* __restrict__ ln2g,
                                                    const float* __restrict__ ln2b, const float* __restrict__ lw,
                                                    const float* __restrict__ lb, float* __restrict__ repr,
                                                    int* __restrict__ ctr, float* __restrict__ out)
{
    __shared__ float sob[4][128];
    __shared__ float sxatt[4][128];
    __shared__ float sm1[4][256];
    __shared__ float spart[4][128];
    __shared__ float pr[128];
    __shared__ int slast;
    int g0 = blockIdx.x * 4;                 // 16 blocks x 4 graphs
    int t = threadIdx.x, lane = t & 63, wv = t >> 6;

    if (t < 512) sob[t >> 7][t & 127] = ob[(size_t)(g0 + (t >> 7)) * Cc + (t & 127)];
    if (t < 128) pr[t] = 0.f;
    __syncthreads();

    // out-proj: wave per column, weight row register-resident, reused across 4 graphs
    for (int c = wv; c < Cc; c += 16) {
        float w0 = out_w[c * Cc + lane];
        float w1 = out_w[c * Cc + 64 + lane];
        float bc = out_b[c];
        #pragma unroll
        for (int g = 0; g < 4; ++g) {
            float p = fmaf(sob[g][lane], w0, sob[g][64 + lane] * w1);
            #pragma unroll
            for (int off = 32; off > 0; off >>= 1) p += __shfl_xor(p, off);
            if (lane == 0) sxatt[g][c] = p + bc;
        }
    }
    __syncthreads();

    // mlp1: 1024 threads = 256 cols x 4 graphs; mw1 coalesced along j
    {
        int j = t & 255, gi = t >> 8;
        float acc = mb1[j];
        #pragma unroll 8
        for (int k = 0; k < Cc; ++k) acc = fmaf(sxatt[gi][k], mw1[k * HIDn + j], acc);
        sm1[gi][j] = fmaxf(acc, 0.f);
    }
    __syncthreads();

    // mlp2 split-K: 1024 threads = 128 cols x 4 graphs x 2 K-halves; mw2 coalesced along c
    {
        int c = t & 127, gi = (t >> 7) & 3, half = t >> 9;
        int k0 = half * 128;
        float acc = 0.f;
        #pragma unroll 8
        for (int k = 0; k < 128; ++k) acc = fmaf(sm1[gi][k0 + k], mw2[(k0 + k) * Cc + c], acc);
        if (half) spart[gi][c] = acc;
        __syncthreads();
        if (!half) sxatt[gi][c] = sxatt[gi][c] + acc + spart[gi][c] + mb2[c];   // y (residual)
    }
    __syncthreads();

    // LN + relu + per-block accumulate (waves 0..3 = graphs)
    if (t < 256) {
        int g = wv;
        float v0 = sxatt[g][lane], v1 = sxatt[g][64 + lane];
        float s = v0 + v1;
        #pragma unroll
        for (int off = 32; off > 0; off >>= 1) s += __shfl_xor(s, off);
        float mu = s * (1.f / 128.f);
        float d0 = v0 - mu, d1 = v1 - mu;
        float vv = d0 * d0 + d1 * d1;
        #pragma unroll
        for (int off = 32; off > 0; off >>= 1) vv += __shfl_xor(vv, off);
        float rstd = rsqrtf(vv * (1.f / 128.f) + EPSf);
        float z0 = fmaxf(d0 * rstd * ln2g[lane] + ln2b[lane], 0.f);
        float z1 = fmaxf(d1 * rstd * ln2g[64 + lane] + ln2b[64 + lane], 0.f);
        atomicAdd(&pr[lane], z0);
        atomicAdd(&pr[64 + lane], z1);
    }
    __syncthreads();
    if (t < 128) atomicAdd(&repr[t], pr[t]);

    // completion: last-arriving block reduces repr -> logits
    __threadfence();
    __syncthreads();
    if (t == 0) slast = atomicAdd(ctr, 1);
    __syncthreads();
    if (slast == 15) {
        __threadfence();
        __shared__ float r0s[128], r1s[128];
        if (t < 128) {
            float r = __hip_atomic_load(&repr[t], __ATOMIC_RELAXED, __HIP_MEMORY_SCOPE_AGENT);
            r0s[t] = r * lw[t * 2 + 0];
            r1s[t] = r * lw[t * 2 + 1];
        }
        __syncthreads();
        for (int s2 = 64; s2 > 0; s2 >>= 1) {
            if (t < s2) { r0s[t] += r0s[t + s2]; r1s[t] += r1s[t + s2]; }
            __syncthreads();
        }
        if (t == 0) { out[0] = r0s[0] + lb[0]; out[1] = r1s[0] + lb[1]; }
    }
}

extern "C" void kernel_launch(void* const* d_in, const int* in_sizes, int n_in,
                              void* d_out, int out_size, void* d_ws, size_t ws_size,
                              hipStream_t stream)
{
    const float* x     = (const float*)d_in[0];
    const int*   ei    = (const int*)d_in[1];
    const float* W0    = (const float*)d_in[2];
    const float* b0    = (const float*)d_in[3];
    const float* W1    = (const float*)d_in[4];
    const float* b1    = (const float*)d_in[5];
    const float* in_w  = (const float*)d_in[6];
    const float* in_b  = (const float*)d_in[7];
    const float* out_w = (const float*)d_in[8];
    const float* out_b = (const float*)d_in[9];
    const float* ln2g  = (const float*)d_in[10];
    const float* ln2b  = (const float*)d_in[11];
    const float* mw1   = (const float*)d_in[12];
    const float* mb1   = (const float*)d_in[13];
    const float* mw2   = (const float*)d_in[14];
    const float* mb2   = (const float*)d_in[15];
    const float* lw    = (const float*)d_in[16];
    const float* lb    = (const float*)d_in[17];
    float* out = (float*)d_out;
    (void)in_sizes; (void)n_in; (void)out_size; (void)ws_size;

    char* ws = (char*)d_ws;
    size_t off = 0;
    auto carve = [&](size_t bytes) { size_t o = off; off += (bytes + 255) & ~(size_t)255; return o; };
    size_t o_ni    = carve((size_t)Gn * Nn * 16);
    size_t o_ep    = carve((size_t)Gn * En * 8);
    size_t o_pool  = carve((size_t)Gn * Cc * 4);
    size_t o_qkv   = carve((size_t)Gn * 384 * 4);
    size_t o_ob    = carve((size_t)Gn * Cc * 4);
    size_t o_repr  = carve((size_t)Cc * 4);
    size_t o_ctr   = carve(256);
    size_t o_H     = carve((size_t)Gn * Nn * Cc * 2);
    size_t o_T     = carve((size_t)Gn * Nn * Cc * 2);
    size_t o_Xb    = carve((size_t)Gn * Nn * Cc * 2);

    int4*  ninfo  = (int4*)(ws + o_ni);
    int2*  epair  = (int2*)(ws + o_ep);
    float* pooled = (float*)(ws + o_pool);
    float* qkvb   = (float*)(ws + o_qkv);
    float* ob     = (float*)(ws + o_ob);
    float* repr   = (float*)(ws + o_repr);
    int*   ctr    = (int*)(ws + o_ctr);
    unsigned short* H  = (unsigned short*)(ws + o_H);
    unsigned short* T  = (unsigned short*)(ws + o_T);
    unsigned short* Xb = (unsigned short*)(ws + o_Xb);

    k_pre<<<2112, 256, 0, stream>>>(ei, x, ninfo, epair, pooled, repr, ctr, Xb);
    k_gemm<<<256, 256, 0, stream>>>(Xb, W0, H);
    k_combine<0><<<2048, 256, 0, stream>>>((const unsigned*)H, epair, ninfo, b0, (unsigned*)T, nullptr);
    k_gemm<<<256, 256, 0, stream>>>(T, W1, H);
    k_combine<1><<<2048, 256, 0, stream>>>((const unsigned*)H, epair, ninfo, b1, nullptr, pooled);
    k_qkv<<<24, 1024, 0, stream>>>(pooled, in_w, in_b, qkvb);
    k_attn<<<4, 1024, 0, stream>>>(qkvb, ob);
    k_tailfinal<<<16, 1024, 0, stream>>>(ob, out_w, out_b, mw1, mb1, mw2, mb2, ln2g, ln2b,
                                         lw, lb, repr, ctr, out);
}

// Round 10
// 178.301 us; speedup vs baseline: 1.3734x; 1.2102x over previous
//
#include <hip/hip_runtime.h>
#include <math.h>

#define Gn 64
#define Nn 1000
#define En 8192
#define Cc 128
#define HIDn 256
#define EPSf 1e-5f

typedef __attribute__((ext_vector_type(8))) short bh8;
typedef __attribute__((ext_vector_type(4))) float fx4;

__device__ __forceinline__ unsigned short f2bf(float f) {
    unsigned u = __float_as_uint(f);
    u += 0x7fffu + ((u >> 16) & 1u);
    return (unsigned short)(u >> 16);
}
__device__ __forceinline__ float bflo(unsigned u) { return __uint_as_float(u << 16); }
__device__ __forceinline__ float bfhi(unsigned u) { return __uint_as_float(u & 0xffff0000u); }

// ---- pre: blocks 0..63 prep(graph b) | block 64: W0->Wt0g bf16^T | block 65: W1->Wt1g ----
__global__ __launch_bounds__(256) void k_pre(const int* __restrict__ ei,
                                             const float* __restrict__ W0, const float* __restrict__ W1,
                                             int4* __restrict__ ninfo, int2* __restrict__ epair,
                                             float* __restrict__ pooled, float* __restrict__ repr,
                                             int* __restrict__ ctr,
                                             unsigned short* __restrict__ Wt0g,
                                             unsigned short* __restrict__ Wt1g)
{
    __shared__ int   curs[1024];
    __shared__ float dinv_s[1024];
    __shared__ int   wsum[4];
    __shared__ __align__(16) short Wls[128][136];
    int t = threadIdx.x;

    if (blockIdx.x >= 64) {
        // ---- transpose + convert one weight matrix: W[k][n] fp32 -> Wt[n][k] bf16 ----
        const float* Wsrc = (blockIdx.x == 64) ? W0 : W1;
        unsigned short* Wdst = (blockIdx.x == 64) ? Wt0g : Wt1g;
        for (int idx = t; idx < 16384; idx += 256) {
            int kI = idx >> 7, n = idx & 127;
            Wls[n][kI] = (short)f2bf(Wsrc[idx]);
        }
        __syncthreads();
        for (int idx = t; idx < 2048; idx += 256) {       // 2048 chunks of 8 shorts
            int n = idx >> 4, kc = idx & 15;
            bh8 v = *(const bh8*)&Wls[n][kc * 8];
            *(bh8*)(Wdst + (size_t)idx * 8) = v;          // row-major [n][k]
        }
        return;
    }

    // ---------------- prep (256 threads, wave-scan CSR build) ----------------
    int g = blockIdx.x;
    const int* srcp = ei + (size_t)g * 2 * En;
    const int* dstp = srcp + En;
    int lane = t & 63, wv = t >> 6;

    #pragma unroll
    for (int j = 0; j < 4; ++j) curs[t * 4 + j] = 0;
    __syncthreads();
    for (int e = t; e < En; e += 256) atomicAdd(&curs[dstp[e]], 1);
    __syncthreads();

    int base = t * 4;
    int d0 = curs[base], d1 = curs[base + 1], d2 = curs[base + 2], d3 = curs[base + 3];
    int s = d0 + d1 + d2 + d3;
    int v = s;
    #pragma unroll
    for (int off = 1; off <= 32; off <<= 1) {
        int u = __shfl_up(v, off);
        if (lane >= off) v += u;
    }
    if (lane == 63) wsum[wv] = v;
    __syncthreads();
    int woff = 0;
    #pragma unroll
    for (int w = 0; w < 4; ++w) if (w < wv) woff += wsum[w];
    int e0 = woff + v - s;
    int e1 = e0 + d0, e2 = e1 + d1, e3 = e2 + d2;
    float dv0 = rsqrtf((float)d0 + 1.f), dv1 = rsqrtf((float)d1 + 1.f);
    float dv2 = rsqrtf((float)d2 + 1.f), dv3 = rsqrtf((float)d3 + 1.f);
    curs[base] = e0; curs[base + 1] = e1; curs[base + 2] = e2; curs[base + 3] = e3;
    dinv_s[base] = dv0; dinv_s[base + 1] = dv1; dinv_s[base + 2] = dv2; dinv_s[base + 3] = dv3;
    if (base < Nn)     ninfo[g * Nn + base]     = make_int4(e0, d0, __float_as_int(dv0 * dv0), 0);
    if (base + 1 < Nn) ninfo[g * Nn + base + 1] = make_int4(e1, d1, __float_as_int(dv1 * dv1), 0);
    if (base + 2 < Nn) ninfo[g * Nn + base + 2] = make_int4(e2, d2, __float_as_int(dv2 * dv2), 0);
    if (base + 3 < Nn) ninfo[g * Nn + base + 3] = make_int4(e3, d3, __float_as_int(dv3 * dv3), 0);
    __syncthreads();

    for (int e = t; e < En; e += 256) {
        int dd = dstp[e], ss = srcp[e];
        int p = atomicAdd(&curs[dd], 1);
        float w = dinv_s[ss] * dinv_s[dd];
        epair[(size_t)g * En + p] = make_int2(ss, __float_as_int(w));
    }
    if (t < Cc) pooled[g * Cc + t] = 0.f;      // accumulated by k_combine<1>
    if (g == 0 && t < Cc) repr[t] = 0.f;       // accumulated by k_tailfinal
    if (g == 0 && t == 0) *ctr = 0;            // completion counter for k_tailfinal
}

// ------ gemm: H[g] = bf16(X[g] @ W), 16 blocks/graph (1024 total), pre-transposed bf16 W ----
// INBF=0: X fp32; INBF=1: X bf16 (T buffer)
template<int INBF>
__global__ __launch_bounds__(256) void k_gemm(const void* __restrict__ Xin,
                                              const unsigned short* __restrict__ Wtg,
                                              unsigned short* __restrict__ Hout)
{
    __shared__ __align__(16) short Wt[128][136];
    int b = blockIdx.x;
    int xcd = b & 7, gg = (b >> 3) & 7, rblk = b >> 6;   // graph g on XCD g%8; rblk 0..15
    int g = xcd + 8 * gg;
    int t = threadIdx.x;
    // stage pre-transposed W (bf16): straight vector copy, no conversion
    for (int idx = t; idx < 2048; idx += 256) {
        int n = idx >> 4, kc = idx & 15;
        bh8 v = *(const bh8*)(Wtg + (size_t)idx * 8);
        *(bh8*)&Wt[n][kc * 8] = v;
    }
    __syncthreads();

    int wave = t >> 6, l = t & 63;
    int lr = l & 15, lg = l >> 4;
    const float* Xf = (const float*)Xin + (size_t)g * Nn * Cc;
    const short* Xh = (const short*)Xin + (size_t)g * Nn * Cc;
    unsigned short* Hg = Hout + (size_t)g * Nn * Cc;

    int rbase = rblk * 64 + wave * 16;
    int r = rbase + lr;
    bool ok = r < Nn;
    bh8 af[4];
    if (INBF) {
        #pragma unroll
        for (int ks = 0; ks < 4; ++ks) {
            if (ok) af[ks] = *(const bh8*)(Xh + (size_t)r * Cc + ks * 32 + lg * 8);
            else    af[ks] = bh8{0, 0, 0, 0, 0, 0, 0, 0};
        }
    } else {
        #pragma unroll
        for (int ks = 0; ks < 4; ++ks) {
            if (ok) {
                const float* xp = Xf + (size_t)r * Cc + ks * 32 + lg * 8;
                fx4 a0 = *(const fx4*)xp;
                fx4 a1 = *(const fx4*)(xp + 4);
                bh8 av;
                av[0] = (short)f2bf(a0[0]); av[1] = (short)f2bf(a0[1]);
                av[2] = (short)f2bf(a0[2]); av[3] = (short)f2bf(a0[3]);
                av[4] = (short)f2bf(a1[0]); av[5] = (short)f2bf(a1[1]);
                av[6] = (short)f2bf(a1[2]); av[7] = (short)f2bf(a1[3]);
                af[ks] = av;
            } else af[ks] = bh8{0, 0, 0, 0, 0, 0, 0, 0};
        }
    }
    fx4 acc[8];
    #pragma unroll
    for (int ct = 0; ct < 8; ++ct) acc[ct] = fx4{0.f, 0.f, 0.f, 0.f};
    #pragma unroll
    for (int ks = 0; ks < 4; ++ks) {
        #pragma unroll
        for (int ct = 0; ct < 8; ++ct) {
            bh8 bfr = *(const bh8*)(&Wt[ct * 16 + lr][ks * 32 + lg * 8]);
            acc[ct] = __builtin_amdgcn_mfma_f32_16x16x32_bf16(af[ks], bfr, acc[ct], 0, 0, 0);
        }
    }
    // C/D layout: col = ct*16 + (lane&15), row = rbase + (lane>>4)*4 + reg
    #pragma unroll
    for (int ct = 0; ct < 8; ++ct) {
        #pragma unroll
        for (int rg = 0; rg < 4; ++rg) {
            int row = rbase + lg * 4 + rg;
            if (row < Nn) Hg[(size_t)row * Cc + ct * 16 + lr] = f2bf(acc[ct][rg]);
        }
    }
}

// ------- combine: tanh(b + selfw*H[n] + sum_e w_e*H[src_e]); 4-deep early-exit gather ------
template<int POOL>
__global__ __launch_bounds__(256) void k_combine(const unsigned* __restrict__ Hb, const int2* __restrict__ epair,
                                                 const int4* __restrict__ ninfo, const float* __restrict__ bias,
                                                 unsigned* __restrict__ Tout, float* __restrict__ pooled)
{
    int b = blockIdx.x;
    int xcd = b & 7, j = b >> 3;
    int g = xcd + 8 * (j & 7);     // same XCD as this graph's GEMM blocks
    int blk = j >> 3;              // 0..31
    int wave = threadIdx.x >> 6, lane = threadIdx.x & 63;
    const unsigned* Hg = Hb + (size_t)g * Nn * 64;   // rows of 64 uint = 128 bf16
    const int2* epg = epair + (size_t)g * En;
    const int4* nig = ninfo + (size_t)g * Nn;
    float2 bb = *(const float2*)(bias + lane * 2);
    float px = 0.f, py = 0.f;
    for (int n = blk * 4 + wave; n < Nn; n += 128) {
        int4 ni = nig[n];
        int st = ni.x, dc = ni.y;
        float sw = __int_as_float(ni.z);
        unsigned hv = Hg[n * 64 + lane];
        float a0x = bflo(hv) * sw + bb.x, a0y = bfhi(hv) * sw + bb.y;
        float a1x = 0.f, a1y = 0.f, a2x = 0.f, a2y = 0.f, a3x = 0.f, a3y = 0.f;
        int e = 0;
        for (; e + 4 <= dc; e += 4) {
            int2 p0 = epg[st + e];
            int2 p1 = epg[st + e + 1];
            int2 p2 = epg[st + e + 2];
            int2 p3 = epg[st + e + 3];
            unsigned r0 = Hg[(size_t)p0.x * 64 + lane];
            unsigned r1 = Hg[(size_t)p1.x * 64 + lane];
            unsigned r2 = Hg[(size_t)p2.x * 64 + lane];
            unsigned r3 = Hg[(size_t)p3.x * 64 + lane];
            float w0 = __int_as_float(p0.y), w1 = __int_as_float(p1.y);
            float w2 = __int_as_float(p2.y), w3 = __int_as_float(p3.y);
            a0x = fmaf(bflo(r0), w0, a0x); a0y = fmaf(bfhi(r0), w0, a0y);
            a1x = fmaf(bflo(r1), w1, a1x); a1y = fmaf(bfhi(r1), w1, a1y);
            a2x = fmaf(bflo(r2), w2, a2x); a2y = fmaf(bfhi(r2), w2, a2y);
            a3x = fmaf(bflo(r3), w3, a3x); a3y = fmaf(bfhi(r3), w3, a3y);
        }
        for (; e < dc; ++e) {
            int2 p0 = epg[st + e];
            unsigned r0 = Hg[(size_t)p0.x * 64 + lane];
            float w0 = __int_as_float(p0.y);
            a0x = fmaf(bflo(r0), w0, a0x); a0y = fmaf(bfhi(r0), w0, a0y);
        }
        float ax = (a0x + a1x) + (a2x + a3x);
        float ay = (a0y + a1y) + (a2y + a3y);
        float tx = tanhf(ax), ty = tanhf(ay);
        if (POOL) { px += tx; py += ty; }
        else Tout[(size_t)(g * Nn + n) * 64 + lane] = ((unsigned)f2bf(ty) << 16) | (unsigned)f2bf(tx);
    }
    if (POOL) {
        atomicAdd(&pooled[g * Cc + lane * 2], px);
        atomicAdd(&pooled[g * Cc + lane * 2 + 1], py);
    }
}

// ---------------- qkv: one wave per output column (coalesced rows + shuffle reduce) -------
__global__ __launch_bounds__(1024) void k_qkv(const float* __restrict__ pooled, const float* __restrict__ in_w,
                                              const float* __restrict__ in_b, float* __restrict__ qkvb)
{
    int t = threadIdx.x, lane = t & 63, wv = t >> 6;
    int c = blockIdx.x * 16 + wv;          // 24 blocks * 16 waves = 384 columns
    const float* wr = in_w + c * Cc;
    float w0 = wr[lane], w1 = wr[64 + lane];
    float bias = in_b[c];
    for (int i = 0; i < Gn; ++i) {
        float p = fmaf(pooled[i * Cc + lane], w0, pooled[i * Cc + 64 + lane] * w1);
        #pragma unroll
        for (int off2 = 32; off2 > 0; off2 >>= 1) p += __shfl_xor(p, off2);
        if (lane == 0) qkvb[i * 384 + c] = p + bias;
    }
}

// ---------------- attn: per-head block, pure LDS ----------------
__global__ __launch_bounds__(1024) void k_attn(const float* __restrict__ qkvb, float* __restrict__ ob)
{
    __shared__ float q[64][33], kk[64][33], v[64][33];
    __shared__ float S[64][64];
    int h = blockIdx.x, t = threadIdx.x;

    for (int idx = t; idx < 2048; idx += 1024) {
        int i = idx >> 5, cc = idx & 31;
        q[i][cc]  = qkvb[i * 384 + h * 32 + cc];
        kk[i][cc] = qkvb[i * 384 + 128 + h * 32 + cc];
        v[i][cc]  = qkvb[i * 384 + 256 + h * 32 + cc];
    }
    __syncthreads();

    for (int idx = t; idx < 4096; idx += 1024) {
        int i = idx >> 6, jj = idx & 63;
        float acc = 0.f;
        #pragma unroll
        for (int d2 = 0; d2 < 32; ++d2) acc = fmaf(q[i][d2], kk[jj][d2], acc);
        S[i][jj] = acc * 0.17677669529663687f;
    }
    __syncthreads();

    int lane = t & 63, w = t >> 6;
    for (int r = w; r < 64; r += 16) {
        float val = S[r][lane];
        float m = val;
        #pragma unroll
        for (int off = 32; off > 0; off >>= 1) m = fmaxf(m, __shfl_xor(m, off));
        float e2 = expf(val - m);
        float ssum = e2;
        #pragma unroll
        for (int off = 32; off > 0; off >>= 1) ssum += __shfl_xor(ssum, off);
        S[r][lane] = e2 / ssum;
    }
    __syncthreads();

    for (int idx = t; idx < 2048; idx += 1024) {
        int i = idx >> 5, d2 = idx & 31;
        float acc = 0.f;
        #pragma unroll 4
        for (int k2 = 0; k2 < 64; ++k2) acc = fmaf(S[i][k2], v[k2][d2], acc);
        ob[i * Cc + h * 32 + d2] = acc;
    }
}

// ---------------- tail+final: 4 graphs/block; last-done block computes logits -------------
__global__ __launch_bounds__(1024) void k_tailfinal(const float* __restrict__ ob, const float* __restrict__ out_w,
                                                    const float* __restrict__ out_b, const float* __restrict__ mw1,
                                                    const float* __restrict__ mb1, const float* __restrict__ mw2,
                                                    const float* __restrict__ mb2, const float* __restrict__ ln2g,
                                                    const float* __restrict__ ln2b, const float* __restrict__ lw,
                                                    const float* __restrict__ lb, float* __restrict__ repr,
                                                    int* __restrict__ ctr, float* __restrict__ out)
{
    __shared__ float sob[4][128];
    __shared__ float sxatt[4][128];
    __shared__ float sm1[4][256];
    __shared__ float spart[4][128];
    __shared__ float pr[128];
    __shared__ int slast;
    int g0 = blockIdx.x * 4;                 // 16 blocks x 4 graphs
    int t = threadIdx.x, lane = t & 63, wv = t >> 6;

    if (t < 512) sob[t >> 7][t & 127] = ob[(size_t)(g0 + (t >> 7)) * Cc + (t & 127)];
    if (t < 128) pr[t] = 0.f;
    __syncthreads();

    // out-proj: wave per column, weight row register-resident, reused across 4 graphs
    for (int c = wv; c < Cc; c += 16) {
        float w0 = out_w[c * Cc + lane];
        float w1 = out_w[c * Cc + 64 + lane];
        float bc = out_b[c];
        #pragma unroll
        for (int g = 0; g < 4; ++g) {
            float p = fmaf(sob[g][lane], w0, sob[g][64 + lane] * w1);
            #pragma unroll
            for (int off = 32; off > 0; off >>= 1) p += __shfl_xor(p, off);
            if (lane == 0) sxatt[g][c] = p + bc;
        }
    }
    __syncthreads();

    // mlp1: 1024 threads = 256 cols x 4 graphs; mw1 coalesced along j
    {
        int j = t & 255, gi = t >> 8;
        float acc = mb1[j];
        #pragma unroll 8
        for (int k = 0; k < Cc; ++k) acc = fmaf(sxatt[gi][k], mw1[k * HIDn + j], acc);
        sm1[gi][j] = fmaxf(acc, 0.f);
    }
    __syncthreads();

    // mlp2 split-K: 1024 threads = 128 cols x 4 graphs x 2 K-halves; mw2 coalesced along c
    {
        int c = t & 127, gi = (t >> 7) & 3, half = t >> 9;
        int k0 = half * 128;
        float acc = 0.f;
        #pragma unroll 8
        for (int k = 0; k < 128; ++k) acc = fmaf(sm1[gi][k0 + k], mw2[(k0 + k) * Cc + c], acc);
        if (half) spart[gi][c] = acc;
        __syncthreads();
        if (!half) sxatt[gi][c] = sxatt[gi][c] + acc + spart[gi][c] + mb2[c];   // y (residual)
    }
    __syncthreads();

    // LN + relu + per-block accumulate (waves 0..3 = graphs)
    if (t < 256) {
        int g = wv;
        float v0 = sxatt[g][lane], v1 = sxatt[g][64 + lane];
        float s = v0 + v1;
        #pragma unroll
        for (int off = 32; off > 0; off >>= 1) s += __shfl_xor(s, off);
        float mu = s * (1.f / 128.f);
        float d0 = v0 - mu, d1 = v1 - mu;
        float vv = d0 * d0 + d1 * d1;
        #pragma unroll
        for (int off = 32; off > 0; off >>= 1) vv += __shfl_xor(vv, off);
        float rstd = rsqrtf(vv * (1.f / 128.f) + EPSf);
        float z0 = fmaxf(d0 * rstd * ln2g[lane] + ln2b[lane], 0.f);
        float z1 = fmaxf(d1 * rstd * ln2g[64 + lane] + ln2b[64 + lane], 0.f);
        atomicAdd(&pr[lane], z0);
        atomicAdd(&pr[64 + lane], z1);
    }
    __syncthreads();
    if (t < 128) atomicAdd(&repr[t], pr[t]);

    // completion: last-arriving block reduces repr -> logits
    __threadfence();
    __syncthreads();
    if (t == 0) slast = atomicAdd(ctr, 1);
    __syncthreads();
    if (slast == 15) {
        __threadfence();
        __shared__ float r0s[128], r1s[128];
        if (t < 128) {
            float r = __hip_atomic_load(&repr[t], __ATOMIC_RELAXED, __HIP_MEMORY_SCOPE_AGENT);
            r0s[t] = r * lw[t * 2 + 0];
            r1s[t] = r * lw[t * 2 + 1];
        }
        __syncthreads();
        for (int s2 = 64; s2 > 0; s2 >>= 1) {
            if (t < s2) { r0s[t] += r0s[t + s2]; r1s[t] += r1s[t + s2]; }
            __syncthreads();
        }
        if (t == 0) { out[0] = r0s[0] + lb[0]; out[1] = r1s[0] + lb[1]; }
    }
}

extern "C" void kernel_launch(void* const* d_in, const int* in_sizes, int n_in,
                              void* d_out, int out_size, void* d_ws, size_t ws_size,
                              hipStream_t stream)
{
    const float* x     = (const float*)d_in[0];
    const int*   ei    = (const int*)d_in[1];
    const float* W0    = (const float*)d_in[2];
    const float* b0    = (const float*)d_in[3];
    const float* W1    = (const float*)d_in[4];
    const float* b1    = (const float*)d_in[5];
    const float* in_w  = (const float*)d_in[6];
    const float* in_b  = (const float*)d_in[7];
    const float* out_w = (const float*)d_in[8];
    const float* out_b = (const float*)d_in[9];
    const float* ln2g  = (const float*)d_in[10];
    const float* ln2b  = (const float*)d_in[11];
    const float* mw1   = (const float*)d_in[12];
    const float* mb1   = (const float*)d_in[13];
    const float* mw2   = (const float*)d_in[14];
    const float* mb2   = (const float*)d_in[15];
    const float* lw    = (const float*)d_in[16];
    const float* lb    = (const float*)d_in[17];
    float* out = (float*)d_out;
    (void)in_sizes; (void)n_in; (void)out_size; (void)ws_size;

    char* ws = (char*)d_ws;
    size_t off = 0;
    auto carve = [&](size_t bytes) { size_t o = off; off += (bytes + 255) & ~(size_t)255; return o; };
    size_t o_ni    = carve((size_t)Gn * Nn * 16);
    size_t o_ep    = carve((size_t)Gn * En * 8);
    size_t o_pool  = carve((size_t)Gn * Cc * 4);
    size_t o_qkv   = carve((size_t)Gn * 384 * 4);
    size_t o_ob    = carve((size_t)Gn * Cc * 4);
    size_t o_repr  = carve((size_t)Cc * 4);
    size_t o_ctr   = carve(256);
    size_t o_W0t   = carve((size_t)Cc * Cc * 2);
    size_t o_W1t   = carve((size_t)Cc * Cc * 2);
    size_t o_H     = carve((size_t)Gn * Nn * Cc * 2);
    size_t o_T     = carve((size_t)Gn * Nn * Cc * 2);

    int4*  ninfo  = (int4*)(ws + o_ni);
    int2*  epair  = (int2*)(ws + o_ep);
    float* pooled = (float*)(ws + o_pool);
    float* qkvb   = (float*)(ws + o_qkv);
    float* ob     = (float*)(ws + o_ob);
    float* repr   = (float*)(ws + o_repr);
    int*   ctr    = (int*)(ws + o_ctr);
    unsigned short* Wt0g = (unsigned short*)(ws + o_W0t);
    unsigned short* Wt1g = (unsigned short*)(ws + o_W1t);
    unsigned short* H  = (unsigned short*)(ws + o_H);
    unsigned short* T  = (unsigned short*)(ws + o_T);

    k_pre<<<66, 256, 0, stream>>>(ei, W0, W1, ninfo, epair, pooled, repr, ctr, Wt0g, Wt1g);
    k_gemm<0><<<1024, 256, 0, stream>>>(x, Wt0g, H);
    k_combine<0><<<2048, 256, 0, stream>>>((const unsigned*)H, epair, ninfo, b0, (unsigned*)T, nullptr);
    k_gemm<1><<<1024, 256, 0, stream>>>(T, Wt1g, H);
    k_combine<1><<<2048, 256, 0, stream>>>((const unsigned*)H, epair, ninfo, b1, nullptr, pooled);
    k_qkv<<<24, 1024, 0, stream>>>(pooled, in_w, in_b, qkvb);
    k_attn<<<4, 1024, 0, stream>>>(qkvb, ob);
    k_tailfinal<<<16, 1024, 0, stream>>>(ob, out_w, out_b, mw1, mb1, mw2, mb2, ln2g, ln2b,
                                         lw, lb, repr, ctr, out);
}

// Round 11
// 170.429 us; speedup vs baseline: 1.4368x; 1.0462x over previous
//
#include <hip/hip_runtime.h>
#include <math.h>

#define Gn 64
#define Nn 1000
#define En 8192
#define Cc 128
#define HIDn 256
#define EPSf 1e-5f

typedef __attribute__((ext_vector_type(8))) short bh8;
typedef __attribute__((ext_vector_type(4))) float fx4;

__device__ __forceinline__ unsigned short f2bf(float f) {
    unsigned u = __float_as_uint(f);
    u += 0x7fffu + ((u >> 16) & 1u);
    return (unsigned short)(u >> 16);
}
__device__ __forceinline__ float bflo(unsigned u) { return __uint_as_float(u << 16); }
__device__ __forceinline__ float bfhi(unsigned u) { return __uint_as_float(u & 0xffff0000u); }

// ---- pre: blocks 0..63 prep(graph b) | block 64: W0->Wt0g bf16^T | block 65: W1->Wt1g ----
__global__ __launch_bounds__(256) void k_pre(const int* __restrict__ ei,
                                             const float* __restrict__ W0, const float* __restrict__ W1,
                                             int4* __restrict__ ninfo, int2* __restrict__ epair,
                                             float* __restrict__ pooled, float* __restrict__ repr,
                                             int* __restrict__ ctr,
                                             unsigned short* __restrict__ Wt0g,
                                             unsigned short* __restrict__ Wt1g)
{
    __shared__ int   curs[1024];
    __shared__ float dinv_s[1024];
    __shared__ int   wsum[4];
    __shared__ __align__(16) short Wls[128][136];
    int t = threadIdx.x;

    if (blockIdx.x >= 64) {
        // ---- transpose + convert one weight matrix: W[k][n] fp32 -> Wt[n][k] bf16 ----
        const float* Wsrc = (blockIdx.x == 64) ? W0 : W1;
        unsigned short* Wdst = (blockIdx.x == 64) ? Wt0g : Wt1g;
        for (int idx = t; idx < 16384; idx += 256) {
            int kI = idx >> 7, n = idx & 127;
            Wls[n][kI] = (short)f2bf(Wsrc[idx]);
        }
        __syncthreads();
        for (int idx = t; idx < 2048; idx += 256) {       // 2048 chunks of 8 shorts
            int n = idx >> 4, kc = idx & 15;
            bh8 v = *(const bh8*)&Wls[n][kc * 8];
            *(bh8*)(Wdst + (size_t)idx * 8) = v;          // row-major [n][k]
        }
        return;
    }

    // ---------------- prep (256 threads, wave-scan CSR build) ----------------
    int g = blockIdx.x;
    const int* srcp = ei + (size_t)g * 2 * En;
    const int* dstp = srcp + En;
    int lane = t & 63, wv = t >> 6;

    #pragma unroll
    for (int j = 0; j < 4; ++j) curs[t * 4 + j] = 0;
    __syncthreads();
    for (int e = t; e < En; e += 256) atomicAdd(&curs[dstp[e]], 1);
    __syncthreads();

    int base = t * 4;
    int d0 = curs[base], d1 = curs[base + 1], d2 = curs[base + 2], d3 = curs[base + 3];
    int s = d0 + d1 + d2 + d3;
    int v = s;
    #pragma unroll
    for (int off = 1; off <= 32; off <<= 1) {
        int u = __shfl_up(v, off);
        if (lane >= off) v += u;
    }
    if (lane == 63) wsum[wv] = v;
    __syncthreads();
    int woff = 0;
    #pragma unroll
    for (int w = 0; w < 4; ++w) if (w < wv) woff += wsum[w];
    int e0 = woff + v - s;
    int e1 = e0 + d0, e2 = e1 + d1, e3 = e2 + d2;
    float dv0 = rsqrtf((float)d0 + 1.f), dv1 = rsqrtf((float)d1 + 1.f);
    float dv2 = rsqrtf((float)d2 + 1.f), dv3 = rsqrtf((float)d3 + 1.f);
    curs[base] = e0; curs[base + 1] = e1; curs[base + 2] = e2; curs[base + 3] = e3;
    dinv_s[base] = dv0; dinv_s[base + 1] = dv1; dinv_s[base + 2] = dv2; dinv_s[base + 3] = dv3;
    if (base < Nn)     ninfo[g * Nn + base]     = make_int4(e0, d0, __float_as_int(dv0 * dv0), 0);
    if (base + 1 < Nn) ninfo[g * Nn + base + 1] = make_int4(e1, d1, __float_as_int(dv1 * dv1), 0);
    if (base + 2 < Nn) ninfo[g * Nn + base + 2] = make_int4(e2, d2, __float_as_int(dv2 * dv2), 0);
    if (base + 3 < Nn) ninfo[g * Nn + base + 3] = make_int4(e3, d3, __float_as_int(dv3 * dv3), 0);
    __syncthreads();

    for (int e = t; e < En; e += 256) {
        int dd = dstp[e], ss = srcp[e];
        int p = atomicAdd(&curs[dd], 1);
        float w = dinv_s[ss] * dinv_s[dd];
        epair[(size_t)g * En + p] = make_int2(ss, __float_as_int(w));
    }
    if (t < Cc) pooled[g * Cc + t] = 0.f;      // accumulated by k_combine<1>
    if (g == 0 && t < Cc) repr[t] = 0.f;       // accumulated by k_tailfinal
    if (g == 0 && t == 0) *ctr = 0;            // completion counter for k_tailfinal
}

// ------ gemm: H[g] = bf16(X[g] @ W), 16 blocks/graph (1024 total), pre-transposed bf16 W ----
// INBF=0: X fp32; INBF=1: X bf16 (T buffer)
template<int INBF>
__global__ __launch_bounds__(256) void k_gemm(const void* __restrict__ Xin,
                                              const unsigned short* __restrict__ Wtg,
                                              unsigned short* __restrict__ Hout)
{
    __shared__ __align__(16) short Wt[128][136];
    int b = blockIdx.x;
    int xcd = b & 7, gg = (b >> 3) & 7, rblk = b >> 6;   // graph g on XCD g%8; rblk 0..15
    int g = xcd + 8 * gg;
    int t = threadIdx.x;
    // stage pre-transposed W (bf16): straight vector copy, no conversion
    for (int idx = t; idx < 2048; idx += 256) {
        int n = idx >> 4, kc = idx & 15;
        bh8 v = *(const bh8*)(Wtg + (size_t)idx * 8);
        *(bh8*)&Wt[n][kc * 8] = v;
    }
    __syncthreads();

    int wave = t >> 6, l = t & 63;
    int lr = l & 15, lg = l >> 4;
    const float* Xf = (const float*)Xin + (size_t)g * Nn * Cc;
    const short* Xh = (const short*)Xin + (size_t)g * Nn * Cc;
    unsigned short* Hg = Hout + (size_t)g * Nn * Cc;

    int rbase = rblk * 64 + wave * 16;
    int r = rbase + lr;
    bool ok = r < Nn;
    bh8 af[4];
    if (INBF) {
        #pragma unroll
        for (int ks = 0; ks < 4; ++ks) {
            if (ok) af[ks] = *(const bh8*)(Xh + (size_t)r * Cc + ks * 32 + lg * 8);
            else    af[ks] = bh8{0, 0, 0, 0, 0, 0, 0, 0};
        }
    } else {
        #pragma unroll
        for (int ks = 0; ks < 4; ++ks) {
            if (ok) {
                const float* xp = Xf + (size_t)r * Cc + ks * 32 + lg * 8;
                fx4 a0 = *(const fx4*)xp;
                fx4 a1 = *(const fx4*)(xp + 4);
                bh8 av;
                av[0] = (short)f2bf(a0[0]); av[1] = (short)f2bf(a0[1]);
                av[2] = (short)f2bf(a0[2]); av[3] = (short)f2bf(a0[3]);
                av[4] = (short)f2bf(a1[0]); av[5] = (short)f2bf(a1[1]);
                av[6] = (short)f2bf(a1[2]); av[7] = (short)f2bf(a1[3]);
                af[ks] = av;
            } else af[ks] = bh8{0, 0, 0, 0, 0, 0, 0, 0};
        }
    }
    fx4 acc[8];
    #pragma unroll
    for (int ct = 0; ct < 8; ++ct) acc[ct] = fx4{0.f, 0.f, 0.f, 0.f};
    #pragma unroll
    for (int ks = 0; ks < 4; ++ks) {
        #pragma unroll
        for (int ct = 0; ct < 8; ++ct) {
            bh8 bfr = *(const bh8*)(&Wt[ct * 16 + lr][ks * 32 + lg * 8]);
            acc[ct] = __builtin_amdgcn_mfma_f32_16x16x32_bf16(af[ks], bfr, acc[ct], 0, 0, 0);
        }
    }
    // C/D layout: col = ct*16 + (lane&15), row = rbase + (lane>>4)*4 + reg
    #pragma unroll
    for (int ct = 0; ct < 8; ++ct) {
        #pragma unroll
        for (int rg = 0; rg < 4; ++rg) {
            int row = rbase + lg * 4 + rg;
            if (row < Nn) Hg[(size_t)row * Cc + ct * 16 + lr] = f2bf(acc[ct][rg]);
        }
    }
}

// ------- combine: tanh(b + selfw*H[n] + sum_e w_e*H[src_e]); 4-deep early-exit gather ------
template<int POOL>
__global__ __launch_bounds__(256) void k_combine(const unsigned* __restrict__ Hb, const int2* __restrict__ epair,
                                                 const int4* __restrict__ ninfo, const float* __restrict__ bias,
                                                 unsigned* __restrict__ Tout, float* __restrict__ pooled)
{
    int b = blockIdx.x;
    int xcd = b & 7, j = b >> 3;
    int g = xcd + 8 * (j & 7);     // same XCD as this graph's GEMM blocks
    int blk = j >> 3;              // 0..31
    int wave = threadIdx.x >> 6, lane = threadIdx.x & 63;
    const unsigned* Hg = Hb + (size_t)g * Nn * 64;   // rows of 64 uint = 128 bf16
    const int2* epg = epair + (size_t)g * En;
    const int4* nig = ninfo + (size_t)g * Nn;
    float2 bb = *(const float2*)(bias + lane * 2);
    float px = 0.f, py = 0.f;
    for (int n = blk * 4 + wave; n < Nn; n += 128) {
        int4 ni = nig[n];
        int st = ni.x, dc = ni.y;
        float sw = __int_as_float(ni.z);
        unsigned hv = Hg[n * 64 + lane];
        float a0x = bflo(hv) * sw + bb.x, a0y = bfhi(hv) * sw + bb.y;
        float a1x = 0.f, a1y = 0.f, a2x = 0.f, a2y = 0.f, a3x = 0.f, a3y = 0.f;
        int e = 0;
        for (; e + 4 <= dc; e += 4) {
            int2 p0 = epg[st + e];
            int2 p1 = epg[st + e + 1];
            int2 p2 = epg[st + e + 2];
            int2 p3 = epg[st + e + 3];
            unsigned r0 = Hg[(size_t)p0.x * 64 + lane];
            unsigned r1 = Hg[(size_t)p1.x * 64 + lane];
            unsigned r2 = Hg[(size_t)p2.x * 64 + lane];
            unsigned r3 = Hg[(size_t)p3.x * 64 + lane];
            float w0 = __int_as_float(p0.y), w1 = __int_as_float(p1.y);
            float w2 = __int_as_float(p2.y), w3 = __int_as_float(p3.y);
            a0x = fmaf(bflo(r0), w0, a0x); a0y = fmaf(bfhi(r0), w0, a0y);
            a1x = fmaf(bflo(r1), w1, a1x); a1y = fmaf(bfhi(r1), w1, a1y);
            a2x = fmaf(bflo(r2), w2, a2x); a2y = fmaf(bfhi(r2), w2, a2y);
            a3x = fmaf(bflo(r3), w3, a3x); a3y = fmaf(bfhi(r3), w3, a3y);
        }
        for (; e < dc; ++e) {
            int2 p0 = epg[st + e];
            unsigned r0 = Hg[(size_t)p0.x * 64 + lane];
            float w0 = __int_as_float(p0.y);
            a0x = fmaf(bflo(r0), w0, a0x); a0y = fmaf(bfhi(r0), w0, a0y);
        }
        float ax = (a0x + a1x) + (a2x + a3x);
        float ay = (a0y + a1y) + (a2y + a3y);
        float tx = tanhf(ax), ty = tanhf(ay);
        if (POOL) { px += tx; py += ty; }
        else Tout[(size_t)(g * Nn + n) * 64 + lane] = ((unsigned)f2bf(ty) << 16) | (unsigned)f2bf(tx);
    }
    if (POOL) {
        atomicAdd(&pooled[g * Cc + lane * 2], px);
        atomicAdd(&pooled[g * Cc + lane * 2 + 1], py);
    }
}

// ---------------- qkv: one wave per output column (coalesced rows + shuffle reduce) -------
__global__ __launch_bounds__(1024) void k_qkv(const float* __restrict__ pooled, const float* __restrict__ in_w,
                                              const float* __restrict__ in_b, float* __restrict__ qkvb)
{
    int t = threadIdx.x, lane = t & 63, wv = t >> 6;
    int c = blockIdx.x * 16 + wv;          // 24 blocks * 16 waves = 384 columns
    const float* wr = in_w + c * Cc;
    float w0 = wr[lane], w1 = wr[64 + lane];
    float bias = in_b[c];
    for (int i = 0; i < Gn; ++i) {
        float p = fmaf(pooled[i * Cc + lane], w0, pooled[i * Cc + 64 + lane] * w1);
        #pragma unroll
        for (int off2 = 32; off2 > 0; off2 >>= 1) p += __shfl_xor(p, off2);
        if (lane == 0) qkvb[i * 384 + c] = p + bias;
    }
}

// ---------------- attn: per-head block, pure LDS ----------------
__global__ __launch_bounds__(1024) void k_attn(const float* __restrict__ qkvb, float* __restrict__ ob)
{
    __shared__ float q[64][33], kk[64][33], v[64][33];
    __shared__ float S[64][64];
    int h = blockIdx.x, t = threadIdx.x;

    for (int idx = t; idx < 2048; idx += 1024) {
        int i = idx >> 5, cc = idx & 31;
        q[i][cc]  = qkvb[i * 384 + h * 32 + cc];
        kk[i][cc] = qkvb[i * 384 + 128 + h * 32 + cc];
        v[i][cc]  = qkvb[i * 384 + 256 + h * 32 + cc];
    }
    __syncthreads();

    for (int idx = t; idx < 4096; idx += 1024) {
        int i = idx >> 6, jj = idx & 63;
        float acc = 0.f;
        #pragma unroll
        for (int d2 = 0; d2 < 32; ++d2) acc = fmaf(q[i][d2], kk[jj][d2], acc);
        S[i][jj] = acc * 0.17677669529663687f;
    }
    __syncthreads();

    int lane = t & 63, w = t >> 6;
    for (int r = w; r < 64; r += 16) {
        float val = S[r][lane];
        float m = val;
        #pragma unroll
        for (int off = 32; off > 0; off >>= 1) m = fmaxf(m, __shfl_xor(m, off));
        float e2 = expf(val - m);
        float ssum = e2;
        #pragma unroll
        for (int off = 32; off > 0; off >>= 1) ssum += __shfl_xor(ssum, off);
        S[r][lane] = e2 / ssum;
    }
    __syncthreads();

    for (int idx = t; idx < 2048; idx += 1024) {
        int i = idx >> 5, d2 = idx & 31;
        float acc = 0.f;
        #pragma unroll 4
        for (int k2 = 0; k2 < 64; ++k2) acc = fmaf(S[i][k2], v[k2][d2], acc);
        ob[i * Cc + h * 32 + d2] = acc;
    }
}

// ------ tail+final: one graph per block, 512 threads, 8-acc ILP split-K MLP ---------------
__global__ __launch_bounds__(512) void k_tailfinal(const float* __restrict__ ob, const float* __restrict__ out_w,
                                                   const float* __restrict__ out_b, const float* __restrict__ mw1,
                                                   const float* __restrict__ mb1, const float* __restrict__ mw2,
                                                   const float* __restrict__ mb2, const float* __restrict__ ln2g,
                                                   const float* __restrict__ ln2b, const float* __restrict__ lw,
                                                   const float* __restrict__ lb, float* __restrict__ repr,
                                                   int* __restrict__ ctr, float* __restrict__ out)
{
    __shared__ float sob[128];
    __shared__ float sxatt[128];
    __shared__ float sm1p[2][256];
    __shared__ float sm1[256];
    __shared__ float sp2[4][128];
    __shared__ float yb[128];
    __shared__ int slast;
    int g = blockIdx.x;                     // 64 blocks, 1 graph each
    int t = threadIdx.x, lane = t & 63, wv = t >> 6;

    if (t < 128) sob[t] = ob[(size_t)g * Cc + t];
    __syncthreads();

    // out-proj: wave per column (coalesced out_w rows), 16 cols/wave
    {
        float o0 = sob[lane], o1 = sob[64 + lane];
        for (int c = wv; c < Cc; c += 8) {
            const float* wr = out_w + c * Cc;
            float p = fmaf(o0, wr[lane], o1 * wr[64 + lane]);
            #pragma unroll
            for (int off = 32; off > 0; off >>= 1) p += __shfl_xor(p, off);
            if (lane == 0) sxatt[c] = p + out_b[c];
        }
    }
    __syncthreads();

    // mlp1: 512 threads = 256 cols x 2 K-halves; 8 independent acc chains
    {
        int jc = t & 255, half = t >> 8;
        int k0b = half * 64;
        float a[8];
        #pragma unroll
        for (int u = 0; u < 8; ++u) a[u] = 0.f;
        for (int k0 = k0b; k0 < k0b + 64; k0 += 8) {
            #pragma unroll
            for (int u = 0; u < 8; ++u)
                a[u] = fmaf(sxatt[k0 + u], mw1[(size_t)(k0 + u) * HIDn + jc], a[u]);
        }
        sm1p[half][jc] = ((a[0] + a[1]) + (a[2] + a[3])) + ((a[4] + a[5]) + (a[6] + a[7]));
        __syncthreads();
        if (t < 256) sm1[t] = fmaxf(sm1p[0][t] + sm1p[1][t] + mb1[t], 0.f);
    }
    __syncthreads();

    // mlp2: 512 threads = 128 cols x 4 K-quarters; 8 independent acc chains
    {
        int c = t & 127, q = t >> 7;
        int j0b = q * 64;
        float a[8];
        #pragma unroll
        for (int u = 0; u < 8; ++u) a[u] = 0.f;
        for (int j0 = j0b; j0 < j0b + 64; j0 += 8) {
            #pragma unroll
            for (int u = 0; u < 8; ++u)
                a[u] = fmaf(sm1[j0 + u], mw2[(size_t)(j0 + u) * Cc + c], a[u]);
        }
        sp2[q][c] = ((a[0] + a[1]) + (a[2] + a[3])) + ((a[4] + a[5]) + (a[6] + a[7]));
        __syncthreads();
        if (t < 128) yb[t] = sxatt[t] + (sp2[0][t] + sp2[1][t]) + (sp2[2][t] + sp2[3][t]) + mb2[t];
    }
    __syncthreads();

    // LN + relu (wave 0) + atomic accumulate into repr
    if (t < 64) {
        float v0 = yb[lane], v1 = yb[64 + lane];
        float s = v0 + v1;
        #pragma unroll
        for (int off = 32; off > 0; off >>= 1) s += __shfl_xor(s, off);
        float mu = s * (1.f / 128.f);
        float d0 = v0 - mu, d1 = v1 - mu;
        float vv = d0 * d0 + d1 * d1;
        #pragma unroll
        for (int off = 32; off > 0; off >>= 1) vv += __shfl_xor(vv, off);
        float rstd = rsqrtf(vv * (1.f / 128.f) + EPSf);
        float z0 = fmaxf(d0 * rstd * ln2g[lane] + ln2b[lane], 0.f);
        float z1 = fmaxf(d1 * rstd * ln2g[64 + lane] + ln2b[64 + lane], 0.f);
        atomicAdd(&repr[lane], z0);
        atomicAdd(&repr[64 + lane], z1);
    }

    // completion: last-arriving block reduces repr -> logits
    __threadfence();
    __syncthreads();
    if (t == 0) slast = atomicAdd(ctr, 1);
    __syncthreads();
    if (slast == 63) {
        __threadfence();
        __shared__ float r0s[128], r1s[128];
        if (t < 128) {
            float r = __hip_atomic_load(&repr[t], __ATOMIC_RELAXED, __HIP_MEMORY_SCOPE_AGENT);
            r0s[t] = r * lw[t * 2 + 0];
            r1s[t] = r * lw[t * 2 + 1];
        }
        __syncthreads();
        for (int s2 = 64; s2 > 0; s2 >>= 1) {
            if (t < s2) { r0s[t] += r0s[t + s2]; r1s[t] += r1s[t + s2]; }
            __syncthreads();
        }
        if (t == 0) { out[0] = r0s[0] + lb[0]; out[1] = r1s[0] + lb[1]; }
    }
}

extern "C" void kernel_launch(void* const* d_in, const int* in_sizes, int n_in,
                              void* d_out, int out_size, void* d_ws, size_t ws_size,
                              hipStream_t stream)
{
    const float* x     = (const float*)d_in[0];
    const int*   ei    = (const int*)d_in[1];
    const float* W0    = (const float*)d_in[2];
    const float* b0    = (const float*)d_in[3];
    const float* W1    = (const float*)d_in[4];
    const float* b1    = (const float*)d_in[5];
    const float* in_w  = (const float*)d_in[6];
    const float* in_b  = (const float*)d_in[7];
    const float* out_w = (const float*)d_in[8];
    const float* out_b = (const float*)d_in[9];
    const float* ln2g  = (const float*)d_in[10];
    const float* ln2b  = (const float*)d_in[11];
    const float* mw1   = (const float*)d_in[12];
    const float* mb1   = (const float*)d_in[13];
    const float* mw2   = (const float*)d_in[14];
    const float* mb2   = (const float*)d_in[15];
    const float* lw    = (const float*)d_in[16];
    const float* lb    = (const float*)d_in[17];
    float* out = (float*)d_out;
    (void)in_sizes; (void)n_in; (void)out_size; (void)ws_size;

    char* ws = (char*)d_ws;
    size_t off = 0;
    auto carve = [&](size_t bytes) { size_t o = off; off += (bytes + 255) & ~(size_t)255; return o; };
    size_t o_ni    = carve((size_t)Gn * Nn * 16);
    size_t o_ep    = carve((size_t)Gn * En * 8);
    size_t o_pool  = carve((size_t)Gn * Cc * 4);
    size_t o_qkv   = carve((size_t)Gn * 384 * 4);
    size_t o_ob    = carve((size_t)Gn * Cc * 4);
    size_t o_repr  = carve((size_t)Cc * 4);
    size_t o_ctr   = carve(256);
    size_t o_W0t   = carve((size_t)Cc * Cc * 2);
    size_t o_W1t   = carve((size_t)Cc * Cc * 2);
    size_t o_H     = carve((size_t)Gn * Nn * Cc * 2);
    size_t o_T     = carve((size_t)Gn * Nn * Cc * 2);

    int4*  ninfo  = (int4*)(ws + o_ni);
    int2*  epair  = (int2*)(ws + o_ep);
    float* pooled = (float*)(ws + o_pool);
    float* qkvb   = (float*)(ws + o_qkv);
    float* ob     = (float*)(ws + o_ob);
    float* repr   = (float*)(ws + o_repr);
    int*   ctr    = (int*)(ws + o_ctr);
    unsigned short* Wt0g = (unsigned short*)(ws + o_W0t);
    unsigned short* Wt1g = (unsigned short*)(ws + o_W1t);
    unsigned short* H  = (unsigned short*)(ws + o_H);
    unsigned short* T  = (unsigned short*)(ws + o_T);

    k_pre<<<66, 256, 0, stream>>>(ei, W0, W1, ninfo, epair, pooled, repr, ctr, Wt0g, Wt1g);
    k_gemm<0><<<1024, 256, 0, stream>>>(x, Wt0g, H);
    k_combine<0><<<2048, 256, 0, stream>>>((const unsigned*)H, epair, ninfo, b0, (unsigned*)T, nullptr);
    k_gemm<1><<<1024, 256, 0, stream>>>(T, Wt1g, H);
    k_combine<1><<<2048, 256, 0, stream>>>((const unsigned*)H, epair, ninfo, b1, nullptr, pooled);
    k_qkv<<<24, 1024, 0, stream>>>(pooled, in_w, in_b, qkvb);
    k_attn<<<4, 1024, 0, stream>>>(qkvb, ob);
    k_tailfinal<<<64, 512, 0, stream>>>(ob, out_w, out_b, mw1, mb1, mw2, mb2, ln2g, ln2b,
                                        lw, lb, repr, ctr, out);
}